// Round 9
// baseline (44.751 us; speedup 1.0000x reference)
//
#include <hip/hip_runtime.h>
#include <math.h>

#define NDB 32
#define DMIN 0.5f
#define DMAX 15.0f
#define VV 4
#define CC 32
#define HH 128
#define WW 160
#define HWHW (HH*WW)
#define CONST_FLOATS 128
#define NXCD 8
#define DPT 4   // depths per thread

typedef _Float16 h8 __attribute__((ext_vector_type(8)));
typedef _Float16 h2 __attribute__((ext_vector_type(2)));

#if defined(__has_builtin)
#  if __has_builtin(__builtin_amdgcn_fdot2)
#    define FDOT2(a,b,c) __builtin_amdgcn_fdot2((a),(b),(c),false)
#  endif
#endif
#ifndef FDOT2
#  define FDOT2(a,b,c) ((c) + (float)(a)[0]*(float)(b)[0] + (float)(a)[1]*(float)(b)[1])
#endif

__device__ __forceinline__ h2 get2(h8 x, int i) {
    return (h2){x[2*i], x[2*i+1]};
}
__device__ __forceinline__ h2 bcast_h2(float w) {
#if defined(__has_builtin) && __has_builtin(__builtin_amdgcn_cvt_pkrtz)
    auto r = __builtin_amdgcn_cvt_pkrtz(w, w);   // __fp16 ext_vector(2)
    h2 out;
    __builtin_memcpy(&out, &r, sizeof(out));     // same bits, zero-cost
    return out;
#else
    _Float16 h = (_Float16)w; return (h2){h, h};
#endif
}

// ws float layout:
// [0..8]  Kinv of K_ref
// per view v (base = 16 + v*16): M[0..8] (= Rv^T Rref), b[9..11] (= Rv^T (t_ref - t_v)),
//                                fx=12, fy=13, cx=14, cy=15
__device__ __forceinline__ void do_setup(const float* __restrict__ K_ref,
                                         const float* __restrict__ c2w_ref,
                                         const float* __restrict__ K_srcs,
                                         const float* __restrict__ c2w_srcs,
                                         float* __restrict__ cw) {
    float a00=K_ref[0], a01=K_ref[1], a02=K_ref[2];
    float a10=K_ref[3], a11=K_ref[4], a12=K_ref[5];
    float a20=K_ref[6], a21=K_ref[7], a22=K_ref[8];
    float det = a00*(a11*a22-a12*a21) - a01*(a10*a22-a12*a20) + a02*(a10*a21-a11*a20);
    float id = 1.0f/det;
    cw[0] = (a11*a22-a12*a21)*id;
    cw[1] = (a02*a21-a01*a22)*id;
    cw[2] = (a01*a12-a02*a11)*id;
    cw[3] = (a12*a20-a10*a22)*id;
    cw[4] = (a00*a22-a02*a20)*id;
    cw[5] = (a02*a10-a00*a12)*id;
    cw[6] = (a10*a21-a11*a20)*id;
    cw[7] = (a01*a20-a00*a21)*id;
    cw[8] = (a00*a11-a01*a10)*id;

    float Rr[9], tr[3];
    for (int i=0;i<3;i++){ for (int j=0;j<3;j++) Rr[i*3+j]=c2w_ref[i*4+j]; tr[i]=c2w_ref[i*4+3]; }

    for (int v=0; v<VV; v++) {
        const float* P = c2w_srcs + v*16;
        float Rv[9], tv[3];
        for (int i=0;i<3;i++){ for (int j=0;j<3;j++) Rv[i*3+j]=P[i*4+j]; tv[i]=P[i*4+3]; }
        float* o = cw + 16 + v*16;
        for (int i=0;i<3;i++) for (int j=0;j<3;j++) {
            float s = 0.f;
            for (int k=0;k<3;k++) s += Rv[k*3+i]*Rr[k*3+j];
            o[i*3+j] = s;
        }
        float dt0 = tr[0]-tv[0], dt1 = tr[1]-tv[1], dt2 = tr[2]-tv[2];
        for (int i=0;i<3;i++) {
            o[9+i] = Rv[0*3+i]*dt0 + Rv[1*3+i]*dt1 + Rv[2*3+i]*dt2;
        }
        const float* Ks = K_srcs + v*9;
        o[12]=Ks[0]; o[13]=Ks[4]; o[14]=Ks[2]; o[15]=Ks[5];
    }
}

// Fused prepass: src transpose (V,C,HW)->(V,HW,C) fp16, ref normalize+transpose
// (C,HW)->(HW,C) fp16, pose setup on thread 0.
__global__ __launch_bounds__(256) void prepass(const float* __restrict__ src,
                                               const float* __restrict__ ref,
                                               const float* __restrict__ K_ref,
                                               const float* __restrict__ c2w_ref,
                                               const float* __restrict__ K_srcs,
                                               const float* __restrict__ c2w_srcs,
                                               _Float16* __restrict__ srcT,
                                               _Float16* __restrict__ refT,
                                               float* __restrict__ cw) {
    int gid = blockIdx.x * 256 + threadIdx.x;
    if (gid < VV*HWHW) {
        int v = gid / HWHW, n = gid % HWHW;
        const float* in = src + (size_t)v*CC*HWHW + n;
        h8* outp = (h8*)(srcT + (size_t)gid*CC);
        #pragma unroll
        for (int cc=0; cc<4; cc++) {
            h8 t;
            #pragma unroll
            for (int j=0; j<8; j++)
                t[j] = (_Float16)in[(size_t)(cc*8+j)*HWHW];
            outp[cc] = t;
        }
    } else if (gid < (VV+1)*HWHW) {
        int n = gid - VV*HWHW;
        float vals[CC];
        float ss = 0.f;
        #pragma unroll
        for (int c=0; c<CC; c++) { float x = ref[(size_t)c*HWHW + n]; vals[c]=x; ss += x*x; }
        float inv = 1.0f / fmaxf(sqrtf(ss), 1e-12f);
        h8* outp = (h8*)(refT + (size_t)n*CC);
        #pragma unroll
        for (int cc=0; cc<4; cc++) {
            h8 t;
            #pragma unroll
            for (int j=0; j<8; j++) t[j] = (_Float16)(vals[cc*8+j]*inv);
            outp[cc] = t;
        }
    }
    if (gid == 0) do_setup(K_ref, c2w_ref, K_srcs, c2w_srcs, cw);
}

// Main kernel: 16 LANES per pixel = 4 views x 4 chunks. Each thread owns ONE
// view's 8 channels: 4 gathers + ~70 VALU per depth, tiny register footprint
// -> 6 waves/SIMD for latency hiding (the R8 bottleneck). Chunk is the
// fastest-varying lane dim so each 4-lane cluster reads a contiguous 64B
// pixel line (one L1 line transaction per corner). Cross-chunk reduction via
// shfl_xor(1,2); cross-view sum via shfl_xor(4,8) on the final scalar.
__global__ __launch_bounds__(256, 6) void cost_volume_g16(
        const _Float16* __restrict__ srcp,  // (V,HW,C) fp16
        const _Float16* __restrict__ refp,  // (HW,C) fp16 normalized
        const float* __restrict__ cw,
        float* __restrict__ out) {
    int b = blockIdx.x;
    int xcd = b & (NXCD-1);
    int t = b >> 3;            // 0..1279
    int dq = t & 7;            // depth-quad id 0..7
    int sHigh = t >> 3;        // 0..159
    int s = xcd + NXCD*sHigh;  // strip 0..1279 (16 pixels each)
    int tid = threadIdx.x;
    int j = tid & 3;           // chunk id within pixel line
    int v = (tid >> 2) & 3;    // view id
    int q = tid >> 4;          // pixel within strip (0..15)
    int n = s*16 + q;
    int j16 = j*16;

    // this lane's ref chunk (16B; 4-lane-cluster contiguous -> coalesced)
    h8 rfv = *(const h8*)((const char*)refp + (n*64 + j16));

    // this lane's view constants
    const float* o = cw + 16 + v*16;
    float M0=o[0],M1=o[1],M2=o[2],M3=o[3],M4=o[4],M5=o[5],M6=o[6],M7=o[7],M8=o[8];
    float B0=o[9],B1=o[10],B2=o[11];
    float fx=o[12],fy=o[13],cx=o[14],cy=o[15];
    const char* vbase = (const char*)srcp + (size_t)v*(HWHW*64);

    int ix = n % WW, iy = n / WW;
    float px = (float)ix, py = (float)iy;

    float rx = cw[0]*px + cw[1]*py + cw[2];
    float ry = cw[3]*px + cw[4]*py + cw[5];
    float rz = cw[6]*px + cw[7]*py + cw[8];

    // depth-independent ray rotation (this view only)
    float mx = M0*rx + M1*ry + M2*rz;
    float my = M3*rx + M4*ry + M5*rz;
    float mz = M6*rx + M7*ry + M8*rz;

    const float invmin = 1.0f/DMAX;
    const float step = (1.0f/DMIN - 1.0f/DMAX) / (float)(NDB-1);

    #pragma unroll
    for (int dd=0; dd<DPT; dd++) {
        int d = dq*DPT + dd;
        float invd = invmin + step * (float)d;
        float zthr = 1e-6f * invd;   // Zraw>1e-6  <=>  az>zthr (az = Zraw*invd)

        // ---- geometry (one view) ----
        float ax = fmaf(B0, invd, mx);
        float ay = fmaf(B1, invd, my);
        float az = fmaf(B2, invd, mz);
        float azc = fmaxf(az, zthr);
        float zr = __builtin_amdgcn_rcpf(azc);
        float u  = fmaf(fx, ax*zr, cx);
        float vv = fmaf(fy, ay*zr, cy);
        float vmask = ((u >= 0.0f) && (u <= (float)(WW-1)) &&
                       (vv >= 0.0f) && (vv <= (float)(HH-1)) && (az > zthr)) ? 1.0f : 0.0f;

        float x0f = floorf(u), y0f = floorf(vv);
        float wx1 = u - x0f,  wy1 = vv - y0f;
        float wx0 = 1.0f - wx1, wy0 = 1.0f - wy1;
        int x0 = (int)x0f, y0 = (int)y0f;
        int cx0 = min(max(x0,0),WW-1),   cx1 = min(max(x0+1,0),WW-1);
        int cy0 = min(max(y0,0),HH-1),   cy1 = min(max(y0+1,0),HH-1);
        int r0 = cy0*(WW*64) + j16, r1 = cy1*(WW*64) + j16;
        int o00 = r0 + cx0*64, o10 = r0 + cx1*64;
        int o01 = r1 + cx0*64, o11 = r1 + cx1*64;

        // ---- 4 gathers in flight ----
        h8 g00 = *(const h8*)(vbase + o00);
        h8 g10 = *(const h8*)(vbase + o10);
        h8 g01 = *(const h8*)(vbase + o01);
        h8 g11 = *(const h8*)(vbase + o11);

        // ---- blend (packed fp16) + dot/norm ----
        h2 w00v = bcast_h2(wx0*wy0), w10v = bcast_h2(wx1*wy0);
        h2 w01v = bcast_h2(wx0*wy1), w11v = bcast_h2(wx1*wy1);
        float dt = 0.f, nm = 0.f;
        #pragma unroll
        for (int i=0; i<4; i++) {
            h2 a = get2(g00,i) * w00v;
            a += get2(g10,i) * w10v;
            a += get2(g01,i) * w01v;
            a += get2(g11,i) * w11v;
            dt = FDOT2(get2(rfv,i), a, dt);
            nm = FDOT2(a, a, nm);
        }

        // ---- chunk reduction (lanes j^1, j^2 same pixel+view) ----
        dt += __shfl_xor(dt, 1); dt += __shfl_xor(dt, 2);
        nm += __shfl_xor(nm, 1); nm += __shfl_xor(nm, 2);

        float sim = vmask * dt * __builtin_amdgcn_rsqf(fmaxf(nm, 1e-24f));
        // ---- view reduction (lanes ^4, ^8 same pixel) ----
        sim += __shfl_xor(sim, 4);
        sim += __shfl_xor(sim, 8);

        int lane16 = tid & 15;
        if (lane16 == 0)      *(float*)((char*)out + (d*(HWHW*4) + n*4)) = sim * (1.0f/(float)VV);
        else if (lane16 == 1) *(float*)((char*)out + ((NDB+d)*(HWHW*4) + n*4)) = __builtin_amdgcn_rcpf(invd);
    }
}

// f32 fallback (no workspace): strided gathers from original layout.
__global__ __launch_bounds__(256) void cost_volume_fallback(
        const float* __restrict__ srcp,  // (V,C,HW)
        const float* __restrict__ refp,  // (C,HW)
        const float* __restrict__ cw,
        float* __restrict__ out) {
    int n = blockIdx.x * 256 + threadIdx.x;
    int d = blockIdx.y;
    if (n >= HWHW) return;
    float px = (float)(n % WW), py = (float)(n / WW);

    float rx = cw[0]*px + cw[1]*py + cw[2];
    float ry = cw[3]*px + cw[4]*py + cw[5];
    float rz = cw[6]*px + cw[7]*py + cw[8];

    const float invmin = 1.0f/DMAX;
    const float step = (1.0f/DMIN - 1.0f/DMAX) / (float)(NDB-1);
    float invd = invmin + step * (float)d;
    float depth = 1.0f / invd;

    float rf[CC];
    float ss = 0.f;
    #pragma unroll
    for (int c=0; c<CC; c++) { float x = refp[(size_t)c*HWHW + n]; rf[c]=x; ss += x*x; }
    float inv = 1.0f / fmaxf(sqrtf(ss), 1e-12f);
    #pragma unroll
    for (int c=0; c<CC; c++) rf[c] *= inv;

    float cost = 0.f;
    #pragma unroll
    for (int v=0; v<VV; v++) {
        const float* o = cw + 16 + v*16;
        float mx = o[0]*rx + o[1]*ry + o[2]*rz;
        float my = o[3]*rx + o[4]*ry + o[5]*rz;
        float mz = o[6]*rx + o[7]*ry + o[8]*rz;
        float X = depth*mx + o[9];
        float Y = depth*my + o[10];
        float Zraw = depth*mz + o[11];
        float Z = fmaxf(Zraw, 1e-6f);
        float u  = o[12]*(X/Z) + o[14];
        float vv = o[13]*(Y/Z) + o[15];
        float gx = 2.0f*(u/(float)(WW-1)) - 1.0f;
        float gy = 2.0f*(vv/(float)(HH-1)) - 1.0f;
        bool valid = (gx >= -1.0f) && (gx <= 1.0f) && (gy >= -1.0f) && (gy <= 1.0f) && (Zraw > 1e-6f);

        float x0f = floorf(u), y0f = floorf(vv);
        float wx1 = u - x0f,  wy1 = vv - y0f;
        float wx0 = 1.0f - wx1, wy0 = 1.0f - wy1;
        int x0 = (int)x0f, y0 = (int)y0f;
        int x1 = x0 + 1,   y1 = y0 + 1;

        float m00 = (x0>=0 && x0<WW && y0>=0 && y0<HH) ? 1.f : 0.f;
        float m10 = (x1>=0 && x1<WW && y0>=0 && y0<HH) ? 1.f : 0.f;
        float m01 = (x0>=0 && x0<WW && y1>=0 && y1<HH) ? 1.f : 0.f;
        float m11 = (x1>=0 && x1<WW && y1>=0 && y1<HH) ? 1.f : 0.f;
        float w00 = wx0*wy0*m00, w10 = wx1*wy0*m10;
        float w01 = wx0*wy1*m01, w11 = wx1*wy1*m11;

        int cx0 = min(max(x0,0),WW-1), cx1 = min(max(x1,0),WW-1);
        int cy0 = min(max(y0,0),HH-1), cy1 = min(max(y1,0),HH-1);
        int i00 = cy0*WW+cx0, i10 = cy0*WW+cx1;
        int i01 = cy1*WW+cx0, i11 = cy1*WW+cx1;

        float dot = 0.f, nrm = 0.f;
        const float* basep = srcp + (size_t)v*CC*HWHW;
        #pragma unroll
        for (int c=0; c<CC; c++) {
            const float* pc = basep + (size_t)c*HWHW;
            float wcv = w00*pc[i00] + w10*pc[i10] + w01*pc[i01] + w11*pc[i11];
            dot += rf[c]*wcv;
            nrm += wcv*wcv;
        }
        float sim = dot / fmaxf(sqrtf(nrm), 1e-12f);
        cost += valid ? sim : 0.f;
    }

    out[(size_t)d*HWHW + n] = cost * (1.0f/(float)VV);
    out[(size_t)NDB*HWHW + (size_t)d*HWHW + n] = depth;
}

extern "C" void kernel_launch(void* const* d_in, const int* in_sizes, int n_in,
                              void* d_out, int out_size, void* d_ws, size_t ws_size,
                              hipStream_t stream) {
    const float* ref_feat  = (const float*)d_in[0];
    const float* src_feats = (const float*)d_in[1];
    const float* K_ref     = (const float*)d_in[2];
    const float* c2w_ref   = (const float*)d_in[3];
    const float* K_srcs    = (const float*)d_in[4];
    const float* c2w_srcs  = (const float*)d_in[5];
    float* out = (float*)d_out;
    float* ws  = (float*)d_ws;

    size_t need_bytes = (size_t)CONST_FLOATS*sizeof(float)
                      + (size_t)(VV+1)*HWHW*CC*sizeof(_Float16);

    if (ws_size >= need_bytes) {
        _Float16* srcT = (_Float16*)(ws + CONST_FLOATS);
        _Float16* refT = srcT + (size_t)VV*HWHW*CC;
        prepass<<<((VV+1)*HWHW + 255)/256, 256, 0, stream>>>(
            src_feats, ref_feat, K_ref, c2w_ref, K_srcs, c2w_srcs, srcT, refT, ws);
        // 1280 strips (16 px) x 8 depth-quads, XCD-swizzled
        cost_volume_g16<<<(HWHW/16)*(NDB/DPT), 256, 0, stream>>>(srcT, refT, ws, out);
    } else {
        prepass<<<1, 1, 0, stream>>>(
            src_feats, ref_feat, K_ref, c2w_ref, K_srcs, c2w_srcs,
            (_Float16*)ws, (_Float16*)ws, ws);  // only gid==0 setup matters
        dim3 grid(HWHW/256, NDB);
        cost_volume_fallback<<<grid, 256, 0, stream>>>(src_feats, ref_feat, ws, out);
    }
}

// Round 10
// 38.452 us; speedup vs baseline: 1.1638x; 1.1638x over previous
//
#include <hip/hip_runtime.h>
#include <math.h>

#define NDB 32
#define DMIN 0.5f
#define DMAX 15.0f
#define VV 4
#define CC 32
#define HH 128
#define WW 160
#define HWHW (HH*WW)
#define CONST_FLOATS 128
#define NXCD 8
#define DPT 4   // depths per thread

typedef _Float16 h8 __attribute__((ext_vector_type(8)));
typedef _Float16 h2 __attribute__((ext_vector_type(2)));

#if defined(__has_builtin)
#  if __has_builtin(__builtin_amdgcn_fdot2)
#    define FDOT2(a,b,c) __builtin_amdgcn_fdot2((a),(b),(c),false)
#  endif
#endif
#ifndef FDOT2
#  define FDOT2(a,b,c) ((c) + (float)(a)[0]*(float)(b)[0] + (float)(a)[1]*(float)(b)[1])
#endif

__device__ __forceinline__ h2 get2(h8 x, int i) {
    return (h2){x[2*i], x[2*i+1]};
}
// pack two f32 -> h2 bits in an int (v_cvt_pkrtz_f16_f32)
__device__ __forceinline__ int pk_h2(float a, float b) {
#if defined(__has_builtin) && __has_builtin(__builtin_amdgcn_cvt_pkrtz)
    auto r = __builtin_amdgcn_cvt_pkrtz(a, b);
    int out; __builtin_memcpy(&out, &r, 4); return out;
#else
    h2 t = {(_Float16)a, (_Float16)b};
    int out; __builtin_memcpy(&out, &t, 4); return out;
#endif
}
__device__ __forceinline__ h2 int_h2(int w) {
    h2 o; __builtin_memcpy(&o, &w, 4); return o;
}

// ws float layout:
// [0..8]  Kinv of K_ref
// per view v (base = 16 + v*16): M[0..8] (= Rv^T Rref), b[9..11] (= Rv^T (t_ref - t_v)),
//                                fx=12, fy=13, cx=14, cy=15
__device__ __forceinline__ void do_setup(const float* __restrict__ K_ref,
                                         const float* __restrict__ c2w_ref,
                                         const float* __restrict__ K_srcs,
                                         const float* __restrict__ c2w_srcs,
                                         float* __restrict__ cw) {
    float a00=K_ref[0], a01=K_ref[1], a02=K_ref[2];
    float a10=K_ref[3], a11=K_ref[4], a12=K_ref[5];
    float a20=K_ref[6], a21=K_ref[7], a22=K_ref[8];
    float det = a00*(a11*a22-a12*a21) - a01*(a10*a22-a12*a20) + a02*(a10*a21-a11*a20);
    float id = 1.0f/det;
    cw[0] = (a11*a22-a12*a21)*id;
    cw[1] = (a02*a21-a01*a22)*id;
    cw[2] = (a01*a12-a02*a11)*id;
    cw[3] = (a12*a20-a10*a22)*id;
    cw[4] = (a00*a22-a02*a20)*id;
    cw[5] = (a02*a10-a00*a12)*id;
    cw[6] = (a10*a21-a11*a20)*id;
    cw[7] = (a01*a20-a00*a21)*id;
    cw[8] = (a00*a11-a01*a10)*id;

    float Rr[9], tr[3];
    for (int i=0;i<3;i++){ for (int j=0;j<3;j++) Rr[i*3+j]=c2w_ref[i*4+j]; tr[i]=c2w_ref[i*4+3]; }

    for (int v=0; v<VV; v++) {
        const float* P = c2w_srcs + v*16;
        float Rv[9], tv[3];
        for (int i=0;i<3;i++){ for (int j=0;j<3;j++) Rv[i*3+j]=P[i*4+j]; tv[i]=P[i*4+3]; }
        float* o = cw + 16 + v*16;
        for (int i=0;i<3;i++) for (int j=0;j<3;j++) {
            float s = 0.f;
            for (int k=0;k<3;k++) s += Rv[k*3+i]*Rr[k*3+j];
            o[i*3+j] = s;
        }
        float dt0 = tr[0]-tv[0], dt1 = tr[1]-tv[1], dt2 = tr[2]-tv[2];
        for (int i=0;i<3;i++) {
            o[9+i] = Rv[0*3+i]*dt0 + Rv[1*3+i]*dt1 + Rv[2*3+i]*dt2;
        }
        const float* Ks = K_srcs + v*9;
        o[12]=Ks[0]; o[13]=Ks[4]; o[14]=Ks[2]; o[15]=Ks[5];
    }
}

// Fused prepass: src transpose (V,C,HW)->(V,HW,C) fp16, ref normalize+transpose
// (C,HW)->(HW,C) fp16, pose setup on thread 0.
__global__ __launch_bounds__(256) void prepass(const float* __restrict__ src,
                                               const float* __restrict__ ref,
                                               const float* __restrict__ K_ref,
                                               const float* __restrict__ c2w_ref,
                                               const float* __restrict__ K_srcs,
                                               const float* __restrict__ c2w_srcs,
                                               _Float16* __restrict__ srcT,
                                               _Float16* __restrict__ refT,
                                               float* __restrict__ cw) {
    int gid = blockIdx.x * 256 + threadIdx.x;
    if (gid < VV*HWHW) {
        int v = gid / HWHW, n = gid % HWHW;
        const float* in = src + (size_t)v*CC*HWHW + n;
        h8* outp = (h8*)(srcT + (size_t)gid*CC);
        #pragma unroll
        for (int cc=0; cc<4; cc++) {
            h8 t;
            #pragma unroll
            for (int j=0; j<8; j++)
                t[j] = (_Float16)in[(size_t)(cc*8+j)*HWHW];
            outp[cc] = t;
        }
    } else if (gid < (VV+1)*HWHW) {
        int n = gid - VV*HWHW;
        float vals[CC];
        float ss = 0.f;
        #pragma unroll
        for (int c=0; c<CC; c++) { float x = ref[(size_t)c*HWHW + n]; vals[c]=x; ss += x*x; }
        float inv = 1.0f / fmaxf(sqrtf(ss), 1e-12f);
        h8* outp = (h8*)(refT + (size_t)n*CC);
        #pragma unroll
        for (int cc=0; cc<4; cc++) {
            h8 t;
            #pragma unroll
            for (int j=0; j<8; j++) t[j] = (_Float16)(vals[cc*8+j]*inv);
            outp[cc] = t;
        }
    }
    if (gid == 0) do_setup(K_ref, c2w_ref, K_srcs, c2w_srcs, cw);
}

// Main kernel: QUAD-per-pixel, 4 depths/thread, fp16 features.
// Geometry DEDUP: lane j of each quad computes geometry for view j ONLY
// (1/4 the geometry VALU of R8), then broadcasts 3 words per view via
// width-4 shfl: two h2-packed weight pairs (validity mask pre-folded:
// masked => all weights 0 => dt=nm=0 => sim=0) and one offset word with
// dx/dy step flags packed in the free low bits of the 64B-aligned offset.
__global__ __launch_bounds__(256, 4) void cost_volume_quad(
        const _Float16* __restrict__ srcp,  // (V,HW,C) fp16
        const _Float16* __restrict__ refp,  // (HW,C) fp16 normalized
        const float* __restrict__ cw,
        float* __restrict__ out) {
    int b = blockIdx.x;
    int xcd = b & (NXCD-1);
    int t = b >> 3;            // 0..319
    int dq = t & 7;            // depth-quad id 0..7
    int sHigh = t >> 3;        // 0..39
    int s = xcd + NXCD*sHigh;  // strip 0..319 (64 pixels each)
    int tid = threadIdx.x;
    int j = tid & 3;           // chunk id within pixel == own view id
    int q = tid >> 2;          // pixel within strip
    int n = s*64 + q;
    int j16 = j*16;            // byte offset of this lane's 16B chunk

    // this lane's ref chunk (16B, quad-contiguous -> coalesced)
    h8 rfv = *(const h8*)((const char*)refp + (n*64 + j16));

    // own-view constants (lane-divergent loads, preamble only)
    const float* o = cw + 16 + j*16;
    float M0=o[0],M1=o[1],M2=o[2],M3=o[3],M4=o[4],M5=o[5],M6=o[6],M7=o[7],M8=o[8];
    float B0=o[9],B1=o[10],B2=o[11];
    float fx=o[12],fy=o[13],cxs=o[14],cys=o[15];
    int voff = j * (HWHW*64);  // view base byte offset (multiple of 64)
    const char* sbase = (const char*)srcp;

    int ix = n % WW, iy = n / WW;
    float px = (float)ix, py = (float)iy;

    float rx = cw[0]*px + cw[1]*py + cw[2];
    float ry = cw[3]*px + cw[4]*py + cw[5];
    float rz = cw[6]*px + cw[7]*py + cw[8];

    // depth-independent ray rotation (own view only)
    float mx = M0*rx + M1*ry + M2*rz;
    float my = M3*rx + M4*ry + M5*rz;
    float mz = M6*rx + M7*ry + M8*rz;

    const float invmin = 1.0f/DMAX;
    const float step = (1.0f/DMIN - 1.0f/DMAX) / (float)(NDB-1);

    #pragma unroll
    for (int dd=0; dd<DPT; dd++) {
        int d = dq*DPT + dd;
        float invd = invmin + step * (float)d;
        float zthr = 1e-6f * invd;   // Zraw>1e-6  <=>  az>zthr (az = Zraw*invd)

        // ---- producer: geometry for OWN view ----
        float ax = fmaf(B0, invd, mx);
        float ay = fmaf(B1, invd, my);
        float az = fmaf(B2, invd, mz);
        float azc = fmaxf(az, zthr);
        float zr = __builtin_amdgcn_rcpf(azc);
        float u  = fmaf(fx, ax*zr, cxs);
        float vv = fmaf(fy, ay*zr, cys);
        float vm = ((u >= 0.0f) && (u <= (float)(WW-1)) &&
                    (vv >= 0.0f) && (vv <= (float)(HH-1)) && (az > zthr)) ? 1.0f : 0.0f;

        float x0f = floorf(u), y0f = floorf(vv);
        float wx1 = u - x0f,  wy1 = vv - y0f;
        float wx0 = 1.0f - wx1, wy0 = 1.0f - wy1;
        int x0 = (int)x0f, y0 = (int)y0f;
        int cx0 = min(max(x0,0),WW-1),   cx1 = min(max(x0+1,0),WW-1);
        int cy0 = min(max(y0,0),HH-1),   cy1 = min(max(y0+1,0),HH-1);
        int W01 = pk_h2(wx0*wy0*vm, wx1*wy0*vm);   // {w00,w10} h2, mask folded
        int W23 = pk_h2(wx0*wy1*vm, wx1*wy1*vm);   // {w01,w11} h2
        // offset word: 64B-aligned base + dx flag (bit0) + dy flag (bit1)
        int OFS = voff + cy0*(WW*64) + cx0*64 + (cx1-cx0) + ((cy1-cy0)<<1);

        // ---- consumers: all 16 gathers in flight ----
        h8 g00[VV], g10[VV], g01[VV], g11[VV];
        int wlo[VV], whi[VV];
        #pragma unroll
        for (int v=0; v<VV; v++) {
            int OF = __shfl(OFS, v, 4);
            wlo[v] = __shfl(W01, v, 4);
            whi[v] = __shfl(W23, v, 4);
            int o00 = (OF & ~63) + j16;
            int d64 = (OF & 1) << 6;                 // 0 or 64
            int dW  = (OF & 2) ? (WW*64) : 0;        // 0 or row stride
            g00[v] = *(const h8*)(sbase + o00);
            g10[v] = *(const h8*)(sbase + (o00 + d64));
            g01[v] = *(const h8*)(sbase + (o00 + dW));
            g11[v] = *(const h8*)(sbase + (o00 + d64 + dW));
        }

        // ---- blends (packed fp16) + dot/norm ----
        float dtv[VV], nmv[VV];
        #pragma unroll
        for (int v=0; v<VV; v++) {
            h2 wp = int_h2(wlo[v]);
            h2 wq = int_h2(whi[v]);
            h2 w00v = (h2){wp[0], wp[0]}, w10v = (h2){wp[1], wp[1]};
            h2 w01v = (h2){wq[0], wq[0]}, w11v = (h2){wq[1], wq[1]};
            float dt = 0.f, nm = 0.f;
            #pragma unroll
            for (int i=0; i<4; i++) {
                h2 a = get2(g00[v],i) * w00v;
                a += get2(g10[v],i) * w10v;
                a += get2(g01[v],i) * w01v;
                a += get2(g11[v],i) * w11v;
                dt = FDOT2(get2(rfv,i), a, dt);
                nm = FDOT2(a, a, nm);
            }
            dtv[v] = dt; nmv[v] = nm;
        }

        // ---- batched quad reductions ----
        #pragma unroll
        for (int v=0; v<VV; v++) {
            dtv[v] += __shfl_xor(dtv[v], 1);
            nmv[v] += __shfl_xor(nmv[v], 1);
        }
        #pragma unroll
        for (int v=0; v<VV; v++) {
            dtv[v] += __shfl_xor(dtv[v], 2);
            nmv[v] += __shfl_xor(nmv[v], 2);
        }
        float cost = 0.f;
        #pragma unroll
        for (int v=0; v<VV; v++) {
            cost += dtv[v] * __builtin_amdgcn_rsqf(fmaxf(nmv[v], 1e-24f));
        }

        if (j == 0)      *(float*)((char*)out + (d*(HWHW*4) + n*4)) = cost * (1.0f/(float)VV);
        else if (j == 1) *(float*)((char*)out + ((NDB+d)*(HWHW*4) + n*4)) = __builtin_amdgcn_rcpf(invd);
    }
}

// f32 fallback (no workspace): strided gathers from original layout.
__global__ __launch_bounds__(256) void cost_volume_fallback(
        const float* __restrict__ srcp,  // (V,C,HW)
        const float* __restrict__ refp,  // (C,HW)
        const float* __restrict__ cw,
        float* __restrict__ out) {
    int n = blockIdx.x * 256 + threadIdx.x;
    int d = blockIdx.y;
    if (n >= HWHW) return;
    float px = (float)(n % WW), py = (float)(n / WW);

    float rx = cw[0]*px + cw[1]*py + cw[2];
    float ry = cw[3]*px + cw[4]*py + cw[5];
    float rz = cw[6]*px + cw[7]*py + cw[8];

    const float invmin = 1.0f/DMAX;
    const float step = (1.0f/DMIN - 1.0f/DMAX) / (float)(NDB-1);
    float invd = invmin + step * (float)d;
    float depth = 1.0f / invd;

    float rf[CC];
    float ss = 0.f;
    #pragma unroll
    for (int c=0; c<CC; c++) { float x = refp[(size_t)c*HWHW + n]; rf[c]=x; ss += x*x; }
    float inv = 1.0f / fmaxf(sqrtf(ss), 1e-12f);
    #pragma unroll
    for (int c=0; c<CC; c++) rf[c] *= inv;

    float cost = 0.f;
    #pragma unroll
    for (int v=0; v<VV; v++) {
        const float* o = cw + 16 + v*16;
        float mx = o[0]*rx + o[1]*ry + o[2]*rz;
        float my = o[3]*rx + o[4]*ry + o[5]*rz;
        float mz = o[6]*rx + o[7]*ry + o[8]*rz;
        float X = depth*mx + o[9];
        float Y = depth*my + o[10];
        float Zraw = depth*mz + o[11];
        float Z = fmaxf(Zraw, 1e-6f);
        float u  = o[12]*(X/Z) + o[14];
        float vv = o[13]*(Y/Z) + o[15];
        float gx = 2.0f*(u/(float)(WW-1)) - 1.0f;
        float gy = 2.0f*(vv/(float)(HH-1)) - 1.0f;
        bool valid = (gx >= -1.0f) && (gx <= 1.0f) && (gy >= -1.0f) && (gy <= 1.0f) && (Zraw > 1e-6f);

        float x0f = floorf(u), y0f = floorf(vv);
        float wx1 = u - x0f,  wy1 = vv - y0f;
        float wx0 = 1.0f - wx1, wy0 = 1.0f - wy1;
        int x0 = (int)x0f, y0 = (int)y0f;
        int x1 = x0 + 1,   y1 = y0 + 1;

        float m00 = (x0>=0 && x0<WW && y0>=0 && y0<HH) ? 1.f : 0.f;
        float m10 = (x1>=0 && x1<WW && y0>=0 && y0<HH) ? 1.f : 0.f;
        float m01 = (x0>=0 && x0<WW && y1>=0 && y1<HH) ? 1.f : 0.f;
        float m11 = (x1>=0 && x1<WW && y1>=0 && y1<HH) ? 1.f : 0.f;
        float w00 = wx0*wy0*m00, w10 = wx1*wy0*m10;
        float w01 = wx0*wy1*m01, w11 = wx1*wy1*m11;

        int cx0 = min(max(x0,0),WW-1), cx1 = min(max(x1,0),WW-1);
        int cy0 = min(max(y0,0),HH-1), cy1 = min(max(y1,0),HH-1);
        int i00 = cy0*WW+cx0, i10 = cy0*WW+cx1;
        int i01 = cy1*WW+cx0, i11 = cy1*WW+cx1;

        float dot = 0.f, nrm = 0.f;
        const float* basep = srcp + (size_t)v*CC*HWHW;
        #pragma unroll
        for (int c=0; c<CC; c++) {
            const float* pc = basep + (size_t)c*HWHW;
            float wcv = w00*pc[i00] + w10*pc[i10] + w01*pc[i01] + w11*pc[i11];
            dot += rf[c]*wcv;
            nrm += wcv*wcv;
        }
        float sim = dot / fmaxf(sqrtf(nrm), 1e-12f);
        cost += valid ? sim : 0.f;
    }

    out[(size_t)d*HWHW + n] = cost * (1.0f/(float)VV);
    out[(size_t)NDB*HWHW + (size_t)d*HWHW + n] = depth;
}

extern "C" void kernel_launch(void* const* d_in, const int* in_sizes, int n_in,
                              void* d_out, int out_size, void* d_ws, size_t ws_size,
                              hipStream_t stream) {
    const float* ref_feat  = (const float*)d_in[0];
    const float* src_feats = (const float*)d_in[1];
    const float* K_ref     = (const float*)d_in[2];
    const float* c2w_ref   = (const float*)d_in[3];
    const float* K_srcs    = (const float*)d_in[4];
    const float* c2w_srcs  = (const float*)d_in[5];
    float* out = (float*)d_out;
    float* ws  = (float*)d_ws;

    size_t need_bytes = (size_t)CONST_FLOATS*sizeof(float)
                      + (size_t)(VV+1)*HWHW*CC*sizeof(_Float16);

    if (ws_size >= need_bytes) {
        _Float16* srcT = (_Float16*)(ws + CONST_FLOATS);
        _Float16* refT = srcT + (size_t)VV*HWHW*CC;
        prepass<<<((VV+1)*HWHW + 255)/256, 256, 0, stream>>>(
            src_feats, ref_feat, K_ref, c2w_ref, K_srcs, c2w_srcs, srcT, refT, ws);
        // 320 strips x 8 depth-quads, XCD-swizzled
        cost_volume_quad<<<(HWHW/64)*(NDB/DPT), 256, 0, stream>>>(srcT, refT, ws, out);
    } else {
        prepass<<<1, 1, 0, stream>>>(
            src_feats, ref_feat, K_ref, c2w_ref, K_srcs, c2w_srcs,
            (_Float16*)ws, (_Float16*)ws, ws);  // only gid==0 setup matters
        dim3 grid(HWHW/256, NDB);
        cost_volume_fallback<<<grid, 256, 0, stream>>>(src_feats, ref_feat, ws, out);
    }
}

// Round 11
// 38.148 us; speedup vs baseline: 1.1731x; 1.0080x over previous
//
#include <hip/hip_runtime.h>
#include <math.h>

#define NDB 32
#define DMIN 0.5f
#define DMAX 15.0f
#define VV 4
#define CC 32
#define HH 128
#define WW 160
#define HWHW (HH*WW)
#define CONST_FLOATS 128
#define NXCD 8
#define DPT 4   // depths per thread

typedef _Float16 h8 __attribute__((ext_vector_type(8)));
typedef _Float16 h2 __attribute__((ext_vector_type(2)));

#if defined(__has_builtin)
#  if __has_builtin(__builtin_amdgcn_fdot2)
#    define FDOT2(a,b,c) __builtin_amdgcn_fdot2((a),(b),(c),false)
#  endif
#endif
#ifndef FDOT2
#  define FDOT2(a,b,c) ((c) + (float)(a)[0]*(float)(b)[0] + (float)(a)[1]*(float)(b)[1])
#endif

__device__ __forceinline__ h2 get2(h8 x, int i) {
    return (h2){x[2*i], x[2*i+1]};
}
// pack two f32 -> h2 bits in an int (v_cvt_pkrtz_f16_f32)
__device__ __forceinline__ int pk_h2(float a, float b) {
#if defined(__has_builtin) && __has_builtin(__builtin_amdgcn_cvt_pkrtz)
    auto r = __builtin_amdgcn_cvt_pkrtz(a, b);
    int out; __builtin_memcpy(&out, &r, 4); return out;
#else
    h2 t = {(_Float16)a, (_Float16)b};
    int out; __builtin_memcpy(&out, &t, 4); return out;
#endif
}
__device__ __forceinline__ h2 int_h2(int w) {
    h2 o; __builtin_memcpy(&o, &w, 4); return o;
}

// ---- DPP quad ops (VALU-speed cross-lane, no LDS pipe) ----
// broadcast lane V within each quad: quad_perm[V,V,V,V]
template<int V>
__device__ __forceinline__ int qb_i(int x) {
    return __builtin_amdgcn_mov_dpp(x, (V)|(V<<2)|(V<<4)|(V<<6), 0xF, 0xF, true);
}
// butterfly quad reduction: xor1 (quad_perm[1,0,3,2]=0xB1), xor2 ([2,3,0,1]=0x4E)
__device__ __forceinline__ float qred(float x) {
    int xi; __builtin_memcpy(&xi, &x, 4);
    int a = __builtin_amdgcn_mov_dpp(xi, 0xB1, 0xF, 0xF, true);
    float af; __builtin_memcpy(&af, &a, 4);
    x += af;
    __builtin_memcpy(&xi, &x, 4);
    int b = __builtin_amdgcn_mov_dpp(xi, 0x4E, 0xF, 0xF, true);
    float bf; __builtin_memcpy(&bf, &b, 4);
    return x + bf;
}

// ws float layout:
// [0..8]  Kinv of K_ref
// per view v (base = 16 + v*16): M[0..8] (= Rv^T Rref), b[9..11] (= Rv^T (t_ref - t_v)),
//                                fx=12, fy=13, cx=14, cy=15
__device__ __forceinline__ void do_setup(const float* __restrict__ K_ref,
                                         const float* __restrict__ c2w_ref,
                                         const float* __restrict__ K_srcs,
                                         const float* __restrict__ c2w_srcs,
                                         float* __restrict__ cw) {
    float a00=K_ref[0], a01=K_ref[1], a02=K_ref[2];
    float a10=K_ref[3], a11=K_ref[4], a12=K_ref[5];
    float a20=K_ref[6], a21=K_ref[7], a22=K_ref[8];
    float det = a00*(a11*a22-a12*a21) - a01*(a10*a22-a12*a20) + a02*(a10*a21-a11*a20);
    float id = 1.0f/det;
    cw[0] = (a11*a22-a12*a21)*id;
    cw[1] = (a02*a21-a01*a22)*id;
    cw[2] = (a01*a12-a02*a11)*id;
    cw[3] = (a12*a20-a10*a22)*id;
    cw[4] = (a00*a22-a02*a20)*id;
    cw[5] = (a02*a10-a00*a12)*id;
    cw[6] = (a10*a21-a11*a20)*id;
    cw[7] = (a01*a20-a00*a21)*id;
    cw[8] = (a00*a11-a01*a10)*id;

    float Rr[9], tr[3];
    for (int i=0;i<3;i++){ for (int j=0;j<3;j++) Rr[i*3+j]=c2w_ref[i*4+j]; tr[i]=c2w_ref[i*4+3]; }

    for (int v=0; v<VV; v++) {
        const float* P = c2w_srcs + v*16;
        float Rv[9], tv[3];
        for (int i=0;i<3;i++){ for (int j=0;j<3;j++) Rv[i*3+j]=P[i*4+j]; tv[i]=P[i*4+3]; }
        float* o = cw + 16 + v*16;
        for (int i=0;i<3;i++) for (int j=0;j<3;j++) {
            float s = 0.f;
            for (int k=0;k<3;k++) s += Rv[k*3+i]*Rr[k*3+j];
            o[i*3+j] = s;
        }
        float dt0 = tr[0]-tv[0], dt1 = tr[1]-tv[1], dt2 = tr[2]-tv[2];
        for (int i=0;i<3;i++) {
            o[9+i] = Rv[0*3+i]*dt0 + Rv[1*3+i]*dt1 + Rv[2*3+i]*dt2;
        }
        const float* Ks = K_srcs + v*9;
        o[12]=Ks[0]; o[13]=Ks[4]; o[14]=Ks[2]; o[15]=Ks[5];
    }
}

// Fused prepass: src transpose (V,C,HW)->(V,HW,C) fp16, ref normalize+transpose
// (C,HW)->(HW,C) fp16, pose setup on thread 0.
__global__ __launch_bounds__(256) void prepass(const float* __restrict__ src,
                                               const float* __restrict__ ref,
                                               const float* __restrict__ K_ref,
                                               const float* __restrict__ c2w_ref,
                                               const float* __restrict__ K_srcs,
                                               const float* __restrict__ c2w_srcs,
                                               _Float16* __restrict__ srcT,
                                               _Float16* __restrict__ refT,
                                               float* __restrict__ cw) {
    int gid = blockIdx.x * 256 + threadIdx.x;
    if (gid < VV*HWHW) {
        int v = gid / HWHW, n = gid % HWHW;
        const float* in = src + (size_t)v*CC*HWHW + n;
        h8* outp = (h8*)(srcT + (size_t)gid*CC);
        #pragma unroll
        for (int cc=0; cc<4; cc++) {
            h8 t;
            #pragma unroll
            for (int j=0; j<8; j++)
                t[j] = (_Float16)in[(size_t)(cc*8+j)*HWHW];
            outp[cc] = t;
        }
    } else if (gid < (VV+1)*HWHW) {
        int n = gid - VV*HWHW;
        float vals[CC];
        float ss = 0.f;
        #pragma unroll
        for (int c=0; c<CC; c++) { float x = ref[(size_t)c*HWHW + n]; vals[c]=x; ss += x*x; }
        float inv = 1.0f / fmaxf(sqrtf(ss), 1e-12f);
        h8* outp = (h8*)(refT + (size_t)n*CC);
        #pragma unroll
        for (int cc=0; cc<4; cc++) {
            h8 t;
            #pragma unroll
            for (int j=0; j<8; j++) t[j] = (_Float16)(vals[cc*8+j]*inv);
            outp[cc] = t;
        }
    }
    if (gid == 0) do_setup(K_ref, c2w_ref, K_srcs, c2w_srcs, cw);
}

// Main kernel: QUAD-per-pixel, 4 depths/thread, fp16 features.
// Geometry dedup (lane j = view j producer) + DPP quad_perm for ALL
// cross-lane traffic (broadcast + reductions): VALU-speed movs instead of
// ds_bpermute, removing lgkmcnt stalls from the dependency chain.
__global__ __launch_bounds__(256, 4) void cost_volume_quad(
        const _Float16* __restrict__ srcp,  // (V,HW,C) fp16
        const _Float16* __restrict__ refp,  // (HW,C) fp16 normalized
        const float* __restrict__ cw,
        float* __restrict__ out) {
    int b = blockIdx.x;
    int xcd = b & (NXCD-1);
    int t = b >> 3;            // 0..319
    int dq = t & 7;            // depth-quad id 0..7
    int sHigh = t >> 3;        // 0..39
    int s = xcd + NXCD*sHigh;  // strip 0..319 (64 pixels each)
    int tid = threadIdx.x;
    int j = tid & 3;           // chunk id within pixel == own view id
    int q = tid >> 2;          // pixel within strip
    int n = s*64 + q;
    int j16 = j*16;            // byte offset of this lane's 16B chunk

    // this lane's ref chunk (16B, quad-contiguous -> coalesced)
    h8 rfv = *(const h8*)((const char*)refp + (n*64 + j16));

    // own-view constants (lane-divergent loads, preamble only)
    const float* o = cw + 16 + j*16;
    float M0=o[0],M1=o[1],M2=o[2],M3=o[3],M4=o[4],M5=o[5],M6=o[6],M7=o[7],M8=o[8];
    float B0=o[9],B1=o[10],B2=o[11];
    float fx=o[12],fy=o[13],cxs=o[14],cys=o[15];
    int voff = j * (HWHW*64);  // view base byte offset (multiple of 64)
    const char* sbase = (const char*)srcp;

    int ix = n % WW, iy = n / WW;
    float px = (float)ix, py = (float)iy;

    float rx = cw[0]*px + cw[1]*py + cw[2];
    float ry = cw[3]*px + cw[4]*py + cw[5];
    float rz = cw[6]*px + cw[7]*py + cw[8];

    // depth-independent ray rotation (own view only)
    float mx = M0*rx + M1*ry + M2*rz;
    float my = M3*rx + M4*ry + M5*rz;
    float mz = M6*rx + M7*ry + M8*rz;

    const float invmin = 1.0f/DMAX;
    const float step = (1.0f/DMIN - 1.0f/DMAX) / (float)(NDB-1);

    #pragma unroll
    for (int dd=0; dd<DPT; dd++) {
        int d = dq*DPT + dd;
        float invd = invmin + step * (float)d;
        float zthr = 1e-6f * invd;   // Zraw>1e-6  <=>  az>zthr (az = Zraw*invd)

        // ---- producer: geometry for OWN view ----
        float ax = fmaf(B0, invd, mx);
        float ay = fmaf(B1, invd, my);
        float az = fmaf(B2, invd, mz);
        float azc = fmaxf(az, zthr);
        float zr = __builtin_amdgcn_rcpf(azc);
        float u  = fmaf(fx, ax*zr, cxs);
        float vv = fmaf(fy, ay*zr, cys);
        float vm = ((u >= 0.0f) && (u <= (float)(WW-1)) &&
                    (vv >= 0.0f) && (vv <= (float)(HH-1)) && (az > zthr)) ? 1.0f : 0.0f;

        float x0f = floorf(u), y0f = floorf(vv);
        float wx1 = u - x0f,  wy1 = vv - y0f;
        float wx0 = 1.0f - wx1, wy0 = 1.0f - wy1;
        int x0 = (int)x0f, y0 = (int)y0f;
        int cx0 = min(max(x0,0),WW-1),   cx1 = min(max(x0+1,0),WW-1);
        int cy0 = min(max(y0,0),HH-1),   cy1 = min(max(y0+1,0),HH-1);
        int W01 = pk_h2(wx0*wy0*vm, wx1*wy0*vm);   // {w00,w10} h2, mask folded
        int W23 = pk_h2(wx0*wy1*vm, wx1*wy1*vm);   // {w01,w11} h2
        // offset word: 64B-aligned base + dx flag (bit0) + dy flag (bit1)
        int OFS = voff + cy0*(WW*64) + cx0*64 + (cx1-cx0) + ((cy1-cy0)<<1);

        // ---- DPP broadcast of all views' words ----
        int OFv[VV], wlo[VV], whi[VV];
        OFv[0]=qb_i<0>(OFS); OFv[1]=qb_i<1>(OFS); OFv[2]=qb_i<2>(OFS); OFv[3]=qb_i<3>(OFS);
        wlo[0]=qb_i<0>(W01); wlo[1]=qb_i<1>(W01); wlo[2]=qb_i<2>(W01); wlo[3]=qb_i<3>(W01);
        whi[0]=qb_i<0>(W23); whi[1]=qb_i<1>(W23); whi[2]=qb_i<2>(W23); whi[3]=qb_i<3>(W23);

        // ---- consumers: all 16 gathers in flight ----
        h8 g00[VV], g10[VV], g01[VV], g11[VV];
        #pragma unroll
        for (int v=0; v<VV; v++) {
            int OF = OFv[v];
            int o00 = (OF & ~63) + j16;
            int d64 = (OF & 1) << 6;                 // 0 or 64
            int dW  = (OF & 2) ? (WW*64) : 0;        // 0 or row stride
            g00[v] = *(const h8*)(sbase + o00);
            g10[v] = *(const h8*)(sbase + (o00 + d64));
            g01[v] = *(const h8*)(sbase + (o00 + dW));
            g11[v] = *(const h8*)(sbase + (o00 + d64 + dW));
        }

        // ---- blends (packed fp16) + dot/norm ----
        float dtv[VV], nmv[VV];
        #pragma unroll
        for (int v=0; v<VV; v++) {
            h2 wp = int_h2(wlo[v]);
            h2 wq = int_h2(whi[v]);
            h2 w00v = (h2){wp[0], wp[0]}, w10v = (h2){wp[1], wp[1]};
            h2 w01v = (h2){wq[0], wq[0]}, w11v = (h2){wq[1], wq[1]};
            float dt = 0.f, nm = 0.f;
            #pragma unroll
            for (int i=0; i<4; i++) {
                h2 a = get2(g00[v],i) * w00v;
                a += get2(g10[v],i) * w10v;
                a += get2(g01[v],i) * w01v;
                a += get2(g11[v],i) * w11v;
                dt = FDOT2(get2(rfv,i), a, dt);
                nm = FDOT2(a, a, nm);
            }
            dtv[v] = dt; nmv[v] = nm;
        }

        // ---- DPP quad reductions ----
        #pragma unroll
        for (int v=0; v<VV; v++) {
            dtv[v] = qred(dtv[v]);
            nmv[v] = qred(nmv[v]);
        }
        float cost = 0.f;
        #pragma unroll
        for (int v=0; v<VV; v++) {
            cost += dtv[v] * __builtin_amdgcn_rsqf(fmaxf(nmv[v], 1e-24f));
        }

        if (j == 0)      *(float*)((char*)out + (d*(HWHW*4) + n*4)) = cost * (1.0f/(float)VV);
        else if (j == 1) *(float*)((char*)out + ((NDB+d)*(HWHW*4) + n*4)) = __builtin_amdgcn_rcpf(invd);
    }
}

// f32 fallback (no workspace): strided gathers from original layout.
__global__ __launch_bounds__(256) void cost_volume_fallback(
        const float* __restrict__ srcp,  // (V,C,HW)
        const float* __restrict__ refp,  // (C,HW)
        const float* __restrict__ cw,
        float* __restrict__ out) {
    int n = blockIdx.x * 256 + threadIdx.x;
    int d = blockIdx.y;
    if (n >= HWHW) return;
    float px = (float)(n % WW), py = (float)(n / WW);

    float rx = cw[0]*px + cw[1]*py + cw[2];
    float ry = cw[3]*px + cw[4]*py + cw[5];
    float rz = cw[6]*px + cw[7]*py + cw[8];

    const float invmin = 1.0f/DMAX;
    const float step = (1.0f/DMIN - 1.0f/DMAX) / (float)(NDB-1);
    float invd = invmin + step * (float)d;
    float depth = 1.0f / invd;

    float rf[CC];
    float ss = 0.f;
    #pragma unroll
    for (int c=0; c<CC; c++) { float x = refp[(size_t)c*HWHW + n]; rf[c]=x; ss += x*x; }
    float inv = 1.0f / fmaxf(sqrtf(ss), 1e-12f);
    #pragma unroll
    for (int c=0; c<CC; c++) rf[c] *= inv;

    float cost = 0.f;
    #pragma unroll
    for (int v=0; v<VV; v++) {
        const float* o = cw + 16 + v*16;
        float mx = o[0]*rx + o[1]*ry + o[2]*rz;
        float my = o[3]*rx + o[4]*ry + o[5]*rz;
        float mz = o[6]*rx + o[7]*ry + o[8]*rz;
        float X = depth*mx + o[9];
        float Y = depth*my + o[10];
        float Zraw = depth*mz + o[11];
        float Z = fmaxf(Zraw, 1e-6f);
        float u  = o[12]*(X/Z) + o[14];
        float vv = o[13]*(Y/Z) + o[15];
        float gx = 2.0f*(u/(float)(WW-1)) - 1.0f;
        float gy = 2.0f*(vv/(float)(HH-1)) - 1.0f;
        bool valid = (gx >= -1.0f) && (gx <= 1.0f) && (gy >= -1.0f) && (gy <= 1.0f) && (Zraw > 1e-6f);

        float x0f = floorf(u), y0f = floorf(vv);
        float wx1 = u - x0f,  wy1 = vv - y0f;
        float wx0 = 1.0f - wx1, wy0 = 1.0f - wy1;
        int x0 = (int)x0f, y0 = (int)y0f;
        int x1 = x0 + 1,   y1 = y0 + 1;

        float m00 = (x0>=0 && x0<WW && y0>=0 && y0<HH) ? 1.f : 0.f;
        float m10 = (x1>=0 && x1<WW && y0>=0 && y0<HH) ? 1.f : 0.f;
        float m01 = (x0>=0 && x0<WW && y1>=0 && y1<HH) ? 1.f : 0.f;
        float m11 = (x1>=0 && x1<WW && y1>=0 && y1<HH) ? 1.f : 0.f;
        float w00 = wx0*wy0*m00, w10 = wx1*wy0*m10;
        float w01 = wx0*wy1*m01, w11 = wx1*wy1*m11;

        int cx0 = min(max(x0,0),WW-1), cx1 = min(max(x1,0),WW-1);
        int cy0 = min(max(y0,0),HH-1), cy1 = min(max(y1,0),HH-1);
        int i00 = cy0*WW+cx0, i10 = cy0*WW+cx1;
        int i01 = cy1*WW+cx0, i11 = cy1*WW+cx1;

        float dot = 0.f, nrm = 0.f;
        const float* basep = srcp + (size_t)v*CC*HWHW;
        #pragma unroll
        for (int c=0; c<CC; c++) {
            const float* pc = basep + (size_t)c*HWHW;
            float wcv = w00*pc[i00] + w10*pc[i10] + w01*pc[i01] + w11*pc[i11];
            dot += rf[c]*wcv;
            nrm += wcv*wcv;
        }
        float sim = dot / fmaxf(sqrtf(nrm), 1e-12f);
        cost += valid ? sim : 0.f;
    }

    out[(size_t)d*HWHW + n] = cost * (1.0f/(float)VV);
    out[(size_t)NDB*HWHW + (size_t)d*HWHW + n] = depth;
}

extern "C" void kernel_launch(void* const* d_in, const int* in_sizes, int n_in,
                              void* d_out, int out_size, void* d_ws, size_t ws_size,
                              hipStream_t stream) {
    const float* ref_feat  = (const float*)d_in[0];
    const float* src_feats = (const float*)d_in[1];
    const float* K_ref     = (const float*)d_in[2];
    const float* c2w_ref   = (const float*)d_in[3];
    const float* K_srcs    = (const float*)d_in[4];
    const float* c2w_srcs  = (const float*)d_in[5];
    float* out = (float*)d_out;
    float* ws  = (float*)d_ws;

    size_t need_bytes = (size_t)CONST_FLOATS*sizeof(float)
                      + (size_t)(VV+1)*HWHW*CC*sizeof(_Float16);

    if (ws_size >= need_bytes) {
        _Float16* srcT = (_Float16*)(ws + CONST_FLOATS);
        _Float16* refT = srcT + (size_t)VV*HWHW*CC;
        prepass<<<((VV+1)*HWHW + 255)/256, 256, 0, stream>>>(
            src_feats, ref_feat, K_ref, c2w_ref, K_srcs, c2w_srcs, srcT, refT, ws);
        // 320 strips x 8 depth-quads, XCD-swizzled
        cost_volume_quad<<<(HWHW/64)*(NDB/DPT), 256, 0, stream>>>(srcT, refT, ws, out);
    } else {
        prepass<<<1, 1, 0, stream>>>(
            src_feats, ref_feat, K_ref, c2w_ref, K_srcs, c2w_srcs,
            (_Float16*)ws, (_Float16*)ws, ws);  // only gid==0 setup matters
        dim3 grid(HWHW/256, NDB);
        cost_volume_fallback<<<grid, 256, 0, stream>>>(src_feats, ref_feat, ws, out);
    }
}

// Round 12
// 37.997 us; speedup vs baseline: 1.1778x; 1.0040x over previous
//
#include <hip/hip_runtime.h>
#include <math.h>

#define NDB 32
#define DMIN 0.5f
#define DMAX 15.0f
#define VV 4
#define CC 32
#define HH 128
#define WW 160
#define HWHW (HH*WW)
#define CONST_FLOATS 128
#define NXCD 8
#define DPT 8   // depths per thread

typedef _Float16 h8 __attribute__((ext_vector_type(8)));
typedef _Float16 h2 __attribute__((ext_vector_type(2)));

#if defined(__has_builtin)
#  if __has_builtin(__builtin_amdgcn_fdot2)
#    define FDOT2(a,b,c) __builtin_amdgcn_fdot2((a),(b),(c),false)
#  endif
#endif
#ifndef FDOT2
#  define FDOT2(a,b,c) ((c) + (float)(a)[0]*(float)(b)[0] + (float)(a)[1]*(float)(b)[1])
#endif

__device__ __forceinline__ h2 get2(h8 x, int i) {
    return (h2){x[2*i], x[2*i+1]};
}
// pack two f32 -> h2 bits in an int (v_cvt_pkrtz_f16_f32)
__device__ __forceinline__ int pk_h2(float a, float b) {
#if defined(__has_builtin) && __has_builtin(__builtin_amdgcn_cvt_pkrtz)
    auto r = __builtin_amdgcn_cvt_pkrtz(a, b);
    int out; __builtin_memcpy(&out, &r, 4); return out;
#else
    h2 t = {(_Float16)a, (_Float16)b};
    int out; __builtin_memcpy(&out, &t, 4); return out;
#endif
}
__device__ __forceinline__ h2 int_h2(int w) {
    h2 o; __builtin_memcpy(&o, &w, 4); return o;
}

// ---- DPP quad ops (VALU-speed cross-lane, no LDS pipe) ----
template<int V>
__device__ __forceinline__ int qb_i(int x) {
    return __builtin_amdgcn_mov_dpp(x, (V)|(V<<2)|(V<<4)|(V<<6), 0xF, 0xF, true);
}
// butterfly quad reduction: xor1 (quad_perm[1,0,3,2]=0xB1), xor2 ([2,3,0,1]=0x4E)
__device__ __forceinline__ float qred(float x) {
    int xi; __builtin_memcpy(&xi, &x, 4);
    int a = __builtin_amdgcn_mov_dpp(xi, 0xB1, 0xF, 0xF, true);
    float af; __builtin_memcpy(&af, &a, 4);
    x += af;
    __builtin_memcpy(&xi, &x, 4);
    int b = __builtin_amdgcn_mov_dpp(xi, 0x4E, 0xF, 0xF, true);
    float bf; __builtin_memcpy(&bf, &b, 4);
    return x + bf;
}

// ws float layout:
// [0..8]  Kinv of K_ref
// per view v (base = 16 + v*16): M[0..8] (= Rv^T Rref), b[9..11] (= Rv^T (t_ref - t_v)),
//                                fx=12, fy=13, cx=14, cy=15
__device__ __forceinline__ void do_setup(const float* __restrict__ K_ref,
                                         const float* __restrict__ c2w_ref,
                                         const float* __restrict__ K_srcs,
                                         const float* __restrict__ c2w_srcs,
                                         float* __restrict__ cw) {
    float a00=K_ref[0], a01=K_ref[1], a02=K_ref[2];
    float a10=K_ref[3], a11=K_ref[4], a12=K_ref[5];
    float a20=K_ref[6], a21=K_ref[7], a22=K_ref[8];
    float det = a00*(a11*a22-a12*a21) - a01*(a10*a22-a12*a20) + a02*(a10*a21-a11*a20);
    float id = 1.0f/det;
    cw[0] = (a11*a22-a12*a21)*id;
    cw[1] = (a02*a21-a01*a22)*id;
    cw[2] = (a01*a12-a02*a11)*id;
    cw[3] = (a12*a20-a10*a22)*id;
    cw[4] = (a00*a22-a02*a20)*id;
    cw[5] = (a02*a10-a00*a12)*id;
    cw[6] = (a10*a21-a11*a20)*id;
    cw[7] = (a01*a20-a00*a21)*id;
    cw[8] = (a00*a11-a01*a10)*id;

    float Rr[9], tr[3];
    for (int i=0;i<3;i++){ for (int j=0;j<3;j++) Rr[i*3+j]=c2w_ref[i*4+j]; tr[i]=c2w_ref[i*4+3]; }

    for (int v=0; v<VV; v++) {
        const float* P = c2w_srcs + v*16;
        float Rv[9], tv[3];
        for (int i=0;i<3;i++){ for (int j=0;j<3;j++) Rv[i*3+j]=P[i*4+j]; tv[i]=P[i*4+3]; }
        float* o = cw + 16 + v*16;
        for (int i=0;i<3;i++) for (int j=0;j<3;j++) {
            float s = 0.f;
            for (int k=0;k<3;k++) s += Rv[k*3+i]*Rr[k*3+j];
            o[i*3+j] = s;
        }
        float dt0 = tr[0]-tv[0], dt1 = tr[1]-tv[1], dt2 = tr[2]-tv[2];
        for (int i=0;i<3;i++) {
            o[9+i] = Rv[0*3+i]*dt0 + Rv[1*3+i]*dt1 + Rv[2*3+i]*dt2;
        }
        const float* Ks = K_srcs + v*9;
        o[12]=Ks[0]; o[13]=Ks[4]; o[14]=Ks[2]; o[15]=Ks[5];
    }
}

// Fused prepass: src transpose (V,C,HW)->(V,HW,C) fp16, ref normalize+transpose
// (C,HW)->(HW,C) fp16, pose setup on thread 0.
__global__ __launch_bounds__(256) void prepass(const float* __restrict__ src,
                                               const float* __restrict__ ref,
                                               const float* __restrict__ K_ref,
                                               const float* __restrict__ c2w_ref,
                                               const float* __restrict__ K_srcs,
                                               const float* __restrict__ c2w_srcs,
                                               _Float16* __restrict__ srcT,
                                               _Float16* __restrict__ refT,
                                               float* __restrict__ cw) {
    int gid = blockIdx.x * 256 + threadIdx.x;
    if (gid < VV*HWHW) {
        int v = gid / HWHW, n = gid % HWHW;
        const float* in = src + (size_t)v*CC*HWHW + n;
        h8* outp = (h8*)(srcT + (size_t)gid*CC);
        #pragma unroll
        for (int cc=0; cc<4; cc++) {
            h8 t;
            #pragma unroll
            for (int j=0; j<8; j++)
                t[j] = (_Float16)in[(size_t)(cc*8+j)*HWHW];
            outp[cc] = t;
        }
    } else if (gid < (VV+1)*HWHW) {
        int n = gid - VV*HWHW;
        float vals[CC];
        float ss = 0.f;
        #pragma unroll
        for (int c=0; c<CC; c++) { float x = ref[(size_t)c*HWHW + n]; vals[c]=x; ss += x*x; }
        float inv = 1.0f / fmaxf(sqrtf(ss), 1e-12f);
        h8* outp = (h8*)(refT + (size_t)n*CC);
        #pragma unroll
        for (int cc=0; cc<4; cc++) {
            h8 t;
            #pragma unroll
            for (int j=0; j<8; j++) t[j] = (_Float16)(vals[cc*8+j]*inv);
            outp[cc] = t;
        }
    }
    if (gid == 0) do_setup(K_ref, c2w_ref, K_srcs, c2w_srcs, cw);
}

// Main kernel: QUAD-per-pixel, 8 depths/thread, fp16 features.
// Geometry dedup (lane j = view j producer) + DPP quad_perm for all
// cross-lane traffic. DPT=8 halves amortized preamble (ref load, ray
// rotation, constants) vs DPT=4.
__global__ __launch_bounds__(256, 4) void cost_volume_quad(
        const _Float16* __restrict__ srcp,  // (V,HW,C) fp16
        const _Float16* __restrict__ refp,  // (HW,C) fp16 normalized
        const float* __restrict__ cw,
        float* __restrict__ out) {
    int b = blockIdx.x;
    int xcd = b & (NXCD-1);
    int t = b >> 3;            // 0..159
    int dq = t & 3;            // depth-oct id 0..3
    int sHigh = t >> 2;        // 0..39
    int s = xcd + NXCD*sHigh;  // strip 0..319 (64 pixels each)
    int tid = threadIdx.x;
    int j = tid & 3;           // chunk id within pixel == own view id
    int q = tid >> 2;          // pixel within strip
    int n = s*64 + q;
    int j16 = j*16;            // byte offset of this lane's 16B chunk

    // this lane's ref chunk (16B, quad-contiguous -> coalesced)
    h8 rfv = *(const h8*)((const char*)refp + (n*64 + j16));

    // own-view constants (lane-divergent loads, preamble only)
    const float* o = cw + 16 + j*16;
    float M0=o[0],M1=o[1],M2=o[2],M3=o[3],M4=o[4],M5=o[5],M6=o[6],M7=o[7],M8=o[8];
    float B0=o[9],B1=o[10],B2=o[11];
    float fx=o[12],fy=o[13],cxs=o[14],cys=o[15];
    int voff = j * (HWHW*64);  // view base byte offset (multiple of 64)
    const char* sbase = (const char*)srcp;

    int ix = n % WW, iy = n / WW;
    float px = (float)ix, py = (float)iy;

    float rx = cw[0]*px + cw[1]*py + cw[2];
    float ry = cw[3]*px + cw[4]*py + cw[5];
    float rz = cw[6]*px + cw[7]*py + cw[8];

    // depth-independent ray rotation (own view only)
    float mx = M0*rx + M1*ry + M2*rz;
    float my = M3*rx + M4*ry + M5*rz;
    float mz = M6*rx + M7*ry + M8*rz;

    const float invmin = 1.0f/DMAX;
    const float step = (1.0f/DMIN - 1.0f/DMAX) / (float)(NDB-1);

    #pragma unroll
    for (int dd=0; dd<DPT; dd++) {
        int d = dq*DPT + dd;
        float invd = invmin + step * (float)d;
        float zthr = 1e-6f * invd;   // Zraw>1e-6  <=>  az>zthr (az = Zraw*invd)

        // ---- producer: geometry for OWN view ----
        float ax = fmaf(B0, invd, mx);
        float ay = fmaf(B1, invd, my);
        float az = fmaf(B2, invd, mz);
        float azc = fmaxf(az, zthr);
        float zr = __builtin_amdgcn_rcpf(azc);
        float u  = fmaf(fx, ax*zr, cxs);
        float vv = fmaf(fy, ay*zr, cys);
        float vm = ((u >= 0.0f) && (u <= (float)(WW-1)) &&
                    (vv >= 0.0f) && (vv <= (float)(HH-1)) && (az > zthr)) ? 1.0f : 0.0f;

        float x0f = floorf(u), y0f = floorf(vv);
        float wx1 = u - x0f,  wy1 = vv - y0f;
        float wx0 = 1.0f - wx1, wy0 = 1.0f - wy1;
        int x0 = (int)x0f, y0 = (int)y0f;
        int cx0 = min(max(x0,0),WW-1),   cx1 = min(max(x0+1,0),WW-1);
        int cy0 = min(max(y0,0),HH-1),   cy1 = min(max(y0+1,0),HH-1);
        int W01 = pk_h2(wx0*wy0*vm, wx1*wy0*vm);   // {w00,w10} h2, mask folded
        int W23 = pk_h2(wx0*wy1*vm, wx1*wy1*vm);   // {w01,w11} h2
        // offset word: 64B-aligned base + dx flag (bit0) + dy flag (bit1)
        int OFS = voff + cy0*(WW*64) + cx0*64 + (cx1-cx0) + ((cy1-cy0)<<1);

        // ---- DPP broadcast of all views' words ----
        int OFv[VV], wlo[VV], whi[VV];
        OFv[0]=qb_i<0>(OFS); OFv[1]=qb_i<1>(OFS); OFv[2]=qb_i<2>(OFS); OFv[3]=qb_i<3>(OFS);
        wlo[0]=qb_i<0>(W01); wlo[1]=qb_i<1>(W01); wlo[2]=qb_i<2>(W01); wlo[3]=qb_i<3>(W01);
        whi[0]=qb_i<0>(W23); whi[1]=qb_i<1>(W23); whi[2]=qb_i<2>(W23); whi[3]=qb_i<3>(W23);

        // ---- consumers: all 16 gathers in flight ----
        h8 g00[VV], g10[VV], g01[VV], g11[VV];
        #pragma unroll
        for (int v=0; v<VV; v++) {
            int OF = OFv[v];
            int o00 = (OF & ~63) + j16;
            int d64 = (OF & 1) << 6;                 // 0 or 64
            int dW  = (OF & 2) ? (WW*64) : 0;        // 0 or row stride
            g00[v] = *(const h8*)(sbase + o00);
            g10[v] = *(const h8*)(sbase + (o00 + d64));
            g01[v] = *(const h8*)(sbase + (o00 + dW));
            g11[v] = *(const h8*)(sbase + (o00 + d64 + dW));
        }

        // ---- blends (packed fp16) + dot/norm ----
        float dtv[VV], nmv[VV];
        #pragma unroll
        for (int v=0; v<VV; v++) {
            h2 wp = int_h2(wlo[v]);
            h2 wq = int_h2(whi[v]);
            h2 w00v = (h2){wp[0], wp[0]}, w10v = (h2){wp[1], wp[1]};
            h2 w01v = (h2){wq[0], wq[0]}, w11v = (h2){wq[1], wq[1]};
            float dt = 0.f, nm = 0.f;
            #pragma unroll
            for (int i=0; i<4; i++) {
                h2 a = get2(g00[v],i) * w00v;
                a += get2(g10[v],i) * w10v;
                a += get2(g01[v],i) * w01v;
                a += get2(g11[v],i) * w11v;
                dt = FDOT2(get2(rfv,i), a, dt);
                nm = FDOT2(a, a, nm);
            }
            dtv[v] = dt; nmv[v] = nm;
        }

        // ---- DPP quad reductions ----
        #pragma unroll
        for (int v=0; v<VV; v++) {
            dtv[v] = qred(dtv[v]);
            nmv[v] = qred(nmv[v]);
        }
        float cost = 0.f;
        #pragma unroll
        for (int v=0; v<VV; v++) {
            cost += dtv[v] * __builtin_amdgcn_rsqf(fmaxf(nmv[v], 1e-24f));
        }

        if (j == 0)      *(float*)((char*)out + (d*(HWHW*4) + n*4)) = cost * (1.0f/(float)VV);
        else if (j == 1) *(float*)((char*)out + ((NDB+d)*(HWHW*4) + n*4)) = __builtin_amdgcn_rcpf(invd);
    }
}

// f32 fallback (no workspace): strided gathers from original layout.
__global__ __launch_bounds__(256) void cost_volume_fallback(
        const float* __restrict__ srcp,  // (V,C,HW)
        const float* __restrict__ refp,  // (C,HW)
        const float* __restrict__ cw,
        float* __restrict__ out) {
    int n = blockIdx.x * 256 + threadIdx.x;
    int d = blockIdx.y;
    if (n >= HWHW) return;
    float px = (float)(n % WW), py = (float)(n / WW);

    float rx = cw[0]*px + cw[1]*py + cw[2];
    float ry = cw[3]*px + cw[4]*py + cw[5];
    float rz = cw[6]*px + cw[7]*py + cw[8];

    const float invmin = 1.0f/DMAX;
    const float step = (1.0f/DMIN - 1.0f/DMAX) / (float)(NDB-1);
    float invd = invmin + step * (float)d;
    float depth = 1.0f / invd;

    float rf[CC];
    float ss = 0.f;
    #pragma unroll
    for (int c=0; c<CC; c++) { float x = refp[(size_t)c*HWHW + n]; rf[c]=x; ss += x*x; }
    float inv = 1.0f / fmaxf(sqrtf(ss), 1e-12f);
    #pragma unroll
    for (int c=0; c<CC; c++) rf[c] *= inv;

    float cost = 0.f;
    #pragma unroll
    for (int v=0; v<VV; v++) {
        const float* o = cw + 16 + v*16;
        float mx = o[0]*rx + o[1]*ry + o[2]*rz;
        float my = o[3]*rx + o[4]*ry + o[5]*rz;
        float mz = o[6]*rx + o[7]*ry + o[8]*rz;
        float X = depth*mx + o[9];
        float Y = depth*my + o[10];
        float Zraw = depth*mz + o[11];
        float Z = fmaxf(Zraw, 1e-6f);
        float u  = o[12]*(X/Z) + o[14];
        float vv = o[13]*(Y/Z) + o[15];
        float gx = 2.0f*(u/(float)(WW-1)) - 1.0f;
        float gy = 2.0f*(vv/(float)(HH-1)) - 1.0f;
        bool valid = (gx >= -1.0f) && (gx <= 1.0f) && (gy >= -1.0f) && (gy <= 1.0f) && (Zraw > 1e-6f);

        float x0f = floorf(u), y0f = floorf(vv);
        float wx1 = u - x0f,  wy1 = vv - y0f;
        float wx0 = 1.0f - wx1, wy0 = 1.0f - wy1;
        int x0 = (int)x0f, y0 = (int)y0f;
        int x1 = x0 + 1,   y1 = y0 + 1;

        float m00 = (x0>=0 && x0<WW && y0>=0 && y0<HH) ? 1.f : 0.f;
        float m10 = (x1>=0 && x1<WW && y0>=0 && y0<HH) ? 1.f : 0.f;
        float m01 = (x0>=0 && x0<WW && y1>=0 && y1<HH) ? 1.f : 0.f;
        float m11 = (x1>=0 && x1<WW && y1>=0 && y1<HH) ? 1.f : 0.f;
        float w00 = wx0*wy0*m00, w10 = wx1*wy0*m10;
        float w01 = wx0*wy1*m01, w11 = wx1*wy1*m11;

        int cx0 = min(max(x0,0),WW-1), cx1 = min(max(x1,0),WW-1);
        int cy0 = min(max(y0,0),HH-1), cy1 = min(max(y1,0),HH-1);
        int i00 = cy0*WW+cx0, i10 = cy0*WW+cx1;
        int i01 = cy1*WW+cx0, i11 = cy1*WW+cx1;

        float dot = 0.f, nrm = 0.f;
        const float* basep = srcp + (size_t)v*CC*HWHW;
        #pragma unroll
        for (int c=0; c<CC; c++) {
            const float* pc = basep + (size_t)c*HWHW;
            float wcv = w00*pc[i00] + w10*pc[i10] + w01*pc[i01] + w11*pc[i11];
            dot += rf[c]*wcv;
            nrm += wcv*wcv;
        }
        float sim = dot / fmaxf(sqrtf(nrm), 1e-12f);
        cost += valid ? sim : 0.f;
    }

    out[(size_t)d*HWHW + n] = cost * (1.0f/(float)VV);
    out[(size_t)NDB*HWHW + (size_t)d*HWHW + n] = depth;
}

extern "C" void kernel_launch(void* const* d_in, const int* in_sizes, int n_in,
                              void* d_out, int out_size, void* d_ws, size_t ws_size,
                              hipStream_t stream) {
    const float* ref_feat  = (const float*)d_in[0];
    const float* src_feats = (const float*)d_in[1];
    const float* K_ref     = (const float*)d_in[2];
    const float* c2w_ref   = (const float*)d_in[3];
    const float* K_srcs    = (const float*)d_in[4];
    const float* c2w_srcs  = (const float*)d_in[5];
    float* out = (float*)d_out;
    float* ws  = (float*)d_ws;

    size_t need_bytes = (size_t)CONST_FLOATS*sizeof(float)
                      + (size_t)(VV+1)*HWHW*CC*sizeof(_Float16);

    if (ws_size >= need_bytes) {
        _Float16* srcT = (_Float16*)(ws + CONST_FLOATS);
        _Float16* refT = srcT + (size_t)VV*HWHW*CC;
        prepass<<<((VV+1)*HWHW + 255)/256, 256, 0, stream>>>(
            src_feats, ref_feat, K_ref, c2w_ref, K_srcs, c2w_srcs, srcT, refT, ws);
        // 320 strips x 4 depth-octs, XCD-swizzled
        cost_volume_quad<<<(HWHW/64)*(NDB/DPT), 256, 0, stream>>>(srcT, refT, ws, out);
    } else {
        prepass<<<1, 1, 0, stream>>>(
            src_feats, ref_feat, K_ref, c2w_ref, K_srcs, c2w_srcs,
            (_Float16*)ws, (_Float16*)ws, ws);  // only gid==0 setup matters
        dim3 grid(HWHW/256, NDB);
        cost_volume_fallback<<<grid, 256, 0, stream>>>(src_feats, ref_feat, ws, out);
    }
}